// Round 1
// 1425.860 us; speedup vs baseline: 1.2909x; 1.2909x over previous
//
#include <hip/hip_runtime.h>
#include <cstdint>
#include <cstddef>

// ---------------------------------------------------------------------------
// AttributeAttentionModule: out = softmax((sa@Wq^T+bq)(x@Wk^T+bk)^T/32) (x@Wv^T+bv)
// B=16384, D=3072, H=3, dh=1024.
// Stage 1: cast inputs fp32->bf16 into ws
// Stage 2: fused QKV GEMM — 256x256x32 tiles, 4-deep LDS pipeline with
//          counted vmcnt(8) (never drains in main loop), raw s_barrier,
//          setprio around MFMA clusters, XOR-swizzled LDS (conflict-free),
//          XCD-chunked block swizzle.
// Stage 3: per-row tiny attention (1 wave/row)
// ---------------------------------------------------------------------------

typedef __bf16 bf16x8 __attribute__((ext_vector_type(8)));
typedef float f32x4 __attribute__((ext_vector_type(4)));

#define GLOBAL_AS __attribute__((address_space(1)))
#define LDS_AS __attribute__((address_space(3)))

__device__ __forceinline__ void async_load16(const __bf16* g, __bf16* l) {
    __builtin_amdgcn_global_load_lds((const GLOBAL_AS void*)g, (LDS_AS void*)l,
                                     16, 0, 0);
}

#define DIM 3072
#define BROWS 16384

// ---------------------------------------------------------------------------
// fp32 -> bf16 cast, 8 elements/thread (2x float4 load, 1x 16B store)
// ---------------------------------------------------------------------------
__global__ __launch_bounds__(256) void cast_f32_bf16(
    const float* __restrict__ src, __bf16* __restrict__ dst, int n8) {
    int i = blockIdx.x * 256 + threadIdx.x;
    if (i >= n8) return;
    const float4* s4 = reinterpret_cast<const float4*>(src);
    float4 a = s4[2 * i];
    float4 b = s4[2 * i + 1];
    bf16x8 o;
    o[0] = (__bf16)a.x; o[1] = (__bf16)a.y; o[2] = (__bf16)a.z; o[3] = (__bf16)a.w;
    o[4] = (__bf16)b.x; o[5] = (__bf16)b.y; o[6] = (__bf16)b.z; o[7] = (__bf16)b.w;
    *reinterpret_cast<bf16x8*>(dst + (size_t)i * 8) = o;
}

// ---------------------------------------------------------------------------
// Fused QKV GEMM: C = A @ W^T + bias, A row-major [B,D], W row-major [D,D]
// (both K-contiguous). Grid: 2304 blocks = 64 m-blocks x 36 n-blocks
// (n-block selects projection: 0..11 Q, 12..23 K, 24..35 V).
// Block tile 256x256, K-step 32. 8 waves in 2x4; each wave owns 128x64
// (8x4 fragment grid of 16x16x32 MFMAs, 32 MFMA per K-tile).
//
// Pipeline: 4 LDS buffers (A 16KB + B 16KB each = 128 KB total). Compute
// tile t from buf[t&3] while staging t+3 into buf[(t+3)&3] (which held the
// fully-consumed t-1). Tile boundary: s_waitcnt vmcnt(8) — tiles t+2,t+3
// (8 loads) stay in flight across the barrier; t+1's 4 oldest loads drain.
// Loads therefore lead consumption by ~3 K-tiles (> HBM latency). No
// __syncthreads() in the loop (it would force vmcnt(0) — the old 31%-
// MfmaUtil stall).
//
// LDS layout per tile: row-major [256][32] bf16 (64B rows, 4 chunks of
// 16B). Chunk c of row r stored at slot c ^ (r&3) ^ ((r>>2)&3): per
// quarter-wave, fragment reads land 2 lanes per 4-bank group (free).
// global_load_lds needs contiguous LDS dests, so the swizzle is applied by
// permuting each lane's *global* source chunk (both-sides involution).
// ---------------------------------------------------------------------------

#define WAIT8 asm volatile("s_waitcnt vmcnt(8)" ::: "memory");
#define WAIT4 asm volatile("s_waitcnt vmcnt(4)" ::: "memory");
#define WAIT0 asm volatile("s_waitcnt vmcnt(0)" ::: "memory");

// stage tile T_ (k0 = T_*32) into buffer B_. 4 loads/thread per tile, issued
// in two pairs (P1 during phase 1, P2 during phase 2). 393216 = 128*DIM.
#define STAGE_P1(B_, T_) \
    async_load16(agp + (T_) * 32,          &lds[B_][0]     + tid8); \
    async_load16(wgp + (T_) * 32,          &lds[B_][8192]  + tid8);
#define STAGE_P2(B_, T_) \
    async_load16(agp + (T_) * 32 + 393216, &lds[B_][4096]  + tid8); \
    async_load16(wgp + (T_) * 32 + 393216, &lds[B_][12288] + tid8);

#define MFMA16(ACCROW) \
    _Pragma("unroll") \
    for (int mt = 0; mt < 4; ++mt) \
    _Pragma("unroll") \
    for (int nt = 0; nt < 4; ++nt) \
        acc[(ACCROW) + mt][nt] = __builtin_amdgcn_mfma_f32_16x16x32_bf16( \
            af[mt], bfv[nt], acc[(ACCROW) + mt][nt], 0, 0, 0);

#define LOAD_A(B_, EXTRA) \
    _Pragma("unroll") \
    for (int q = 0; q < 4; ++q) \
        af[q] = *reinterpret_cast<const bf16x8*>( \
            &lds[B_][aofs + (EXTRA) + q * 512]);
#define LOAD_B(B_) \
    _Pragma("unroll") \
    for (int q = 0; q < 4; ++q) \
        bfv[q] = *reinterpret_cast<const bf16x8*>( \
            &lds[B_][8192 + bofs + q * 512]);

// compute tile T_ from buffer B_, staging tile T_+3 into buffer SB_.
#define TILE(B_, SB_, T_, W_) { \
    bf16x8 af[4], bfv[4]; \
    LOAD_A(B_, 0) \
    LOAD_B(B_) \
    STAGE_P1(SB_, (T_) + 3) \
    __builtin_amdgcn_s_setprio(1); \
    MFMA16(0) \
    __builtin_amdgcn_s_setprio(0); \
    __builtin_amdgcn_s_barrier(); \
    LOAD_A(B_, 2048) \
    STAGE_P2(SB_, (T_) + 3) \
    __builtin_amdgcn_s_setprio(1); \
    MFMA16(4) \
    __builtin_amdgcn_s_setprio(0); \
    W_ \
    __builtin_amdgcn_s_barrier(); \
}

#define TILE_NS(B_, W_) { \
    bf16x8 af[4], bfv[4]; \
    LOAD_A(B_, 0) \
    LOAD_B(B_) \
    __builtin_amdgcn_s_setprio(1); \
    MFMA16(0) \
    __builtin_amdgcn_s_setprio(0); \
    __builtin_amdgcn_s_barrier(); \
    LOAD_A(B_, 2048) \
    __builtin_amdgcn_s_setprio(1); \
    MFMA16(4) \
    __builtin_amdgcn_s_setprio(0); \
    W_ \
    __builtin_amdgcn_s_barrier(); \
}

#define TILE_LAST(B_) { \
    bf16x8 af[4], bfv[4]; \
    LOAD_A(B_, 0) \
    LOAD_B(B_) \
    MFMA16(0) \
    LOAD_A(B_, 2048) \
    MFMA16(4) \
}

__global__ __launch_bounds__(512, 2) void gemm_qkv(
    const __bf16* __restrict__ xb, const __bf16* __restrict__ sb,
    const __bf16* __restrict__ wqb, const __bf16* __restrict__ wkb,
    const __bf16* __restrict__ wvb,
    const float* __restrict__ bq, const float* __restrict__ bk,
    const float* __restrict__ bv,
    __bf16* __restrict__ qo, __bf16* __restrict__ ko, __bf16* __restrict__ vo) {

    // 4 pipeline buffers; per buffer: A tile elems [0,8192), B tile [8192,16384)
    __shared__ __bf16 lds[4][16384];

    const int tid  = threadIdx.x;
    const int lane = tid & 63;
    const int wave = tid >> 6;    // 0..7
    const int wm   = wave >> 2;   // 0..1  (m half: 128 rows)
    const int wn   = wave & 3;    // 0..3  (n quarter: 64 cols)

    // XCD-chunked swizzle: 2304 = 8 XCDs x 288; within a chunk bn varies
    // fastest so 36 consecutive blocks share one 1.5 MB A-panel in L2.
    const int bid  = blockIdx.x;
    const int swz  = (bid & 7) * 288 + (bid >> 3);
    const int bn   = swz % 36;
    const int bm   = swz / 36;
    const int proj = bn / 12;             // 0=Q 1=K 2=V
    const int n0   = (bn % 12) * 256;
    const int m0   = bm * 256;

    const __bf16* A = (proj == 0) ? sb : xb;
    const __bf16* W = (proj == 0) ? wqb : (proj == 1 ? wkb : wvb);
    const float*  bias = (proj == 0) ? bq : (proj == 1 ? bk : bv);
    __bf16* O = (proj == 0) ? qo : (proj == 1 ? ko : vo);

    // staging: thread handles chunk idx = l*512+tid (l=0,1): row = idx>>2,
    // stored slot = idx&3, fetched global chunk = slot ^ (row&3) ^ ((row>>2)&3).
    // The XOR terms reduce to per-thread constants (same for both l).
    const int trow = tid >> 2;  // 0..127 (l=0); +128 for l=1
    const int tc   = (tid & 3) ^ ((tid >> 2) & 3) ^ ((tid >> 4) & 3);
    const __bf16* agp = A + (size_t)(m0 + trow) * DIM + tc * 8;
    const __bf16* wgp = W + (size_t)(n0 + trow) * DIM + tc * 8;
    const int tid8 = tid * 8;

    // fragment-read addressing: row r = (wm*128|wn*64) + f*16 + lr, logical
    // chunk lc = lane>>4; stored slot = lc ^ (r&3) ^ ((r>>2)&3), and the row
    // XOR terms collapse to lr bits -> per-thread constant slot.
    const int lr   = lane & 15;
    const int lc   = lane >> 4;
    const int slot = lc ^ (lr & 3) ^ ((lr >> 2) & 3);
    const int aofs = (wm * 128 + lr) * 32 + slot * 8;
    const int bofs = (wn * 64 + lr) * 32 + slot * 8;

    f32x4 acc[8][4];
#pragma unroll
    for (int mt = 0; mt < 8; ++mt)
#pragma unroll
        for (int nt = 0; nt < 4; ++nt)
            acc[mt][nt] = (f32x4){0.f, 0.f, 0.f, 0.f};

    // prologue: stage tiles 0,1,2 (12 loads); wait for tile 0 (oldest 4).
    STAGE_P1(0, 0) STAGE_P2(0, 0)
    STAGE_P1(1, 1) STAGE_P2(1, 1)
    STAGE_P1(2, 2) STAGE_P2(2, 2)
    WAIT8
    __builtin_amdgcn_s_barrier();

    // main loop: 96 K-tiles total; t=0..91 here, staging t+3 (<=94).
    for (int tt = 0; tt < 23; ++tt) {
        const int t = tt * 4;
        TILE(0, 3, t + 0, WAIT8)
        TILE(1, 0, t + 1, WAIT8)
        TILE(2, 1, t + 2, WAIT8)
        TILE(3, 2, t + 3, WAIT8)
    }
    // tail: t=92 stages tile 95; then drain 8 -> 4 -> 0.
    TILE(0, 3, 92, WAIT8)
    TILE_NS(1, WAIT4)
    TILE_NS(2, WAIT0)
    TILE_LAST(3)

    // epilogue: C/D layout col=lane&15, row=(lane>>4)*4+reg
    const int lrow4 = (lane >> 4) * 4;
#pragma unroll
    for (int nt = 0; nt < 4; ++nt) {
        const int n = n0 + wn * 64 + nt * 16 + lr;
        const float bn_f = bias[n];
#pragma unroll
        for (int mt = 0; mt < 8; ++mt) {
            const int mbase = m0 + wm * 128 + mt * 16 + lrow4;
#pragma unroll
            for (int r = 0; r < 4; ++r) {
                O[(size_t)(mbase + r) * DIM + n] =
                    (__bf16)(acc[mt][nt][r] + bn_f);
            }
        }
    }
}

// ---------------------------------------------------------------------------
// Tiny cross-attention: one wave per row. dh=1024 -> lane covers 8 d's per
// half (d = it*512 + lane*8). 9 scores via butterfly reduction.
// ---------------------------------------------------------------------------
__global__ __launch_bounds__(256) void attn_kernel(
    const __bf16* __restrict__ q, const __bf16* __restrict__ k,
    const __bf16* __restrict__ v, float* __restrict__ out) {
    const int wave = threadIdx.x >> 6;
    const int lane = threadIdx.x & 63;
    const size_t b = (size_t)blockIdx.x * 4 + wave;

    const __bf16* qr = q + b * DIM;
    const __bf16* kr = k + b * DIM;
    const __bf16* vr = v + b * DIM;

    float s[3][3] = {{0.f, 0.f, 0.f}, {0.f, 0.f, 0.f}, {0.f, 0.f, 0.f}};

#pragma unroll
    for (int it = 0; it < 2; ++it) {
        const int d0 = it * 512 + lane * 8;
        bf16x8 q8[3], k8[3];
#pragma unroll
        for (int h = 0; h < 3; ++h)
            q8[h] = *reinterpret_cast<const bf16x8*>(qr + h * 1024 + d0);
#pragma unroll
        for (int g = 0; g < 3; ++g)
            k8[g] = *reinterpret_cast<const bf16x8*>(kr + g * 1024 + d0);
#pragma unroll
        for (int h = 0; h < 3; ++h)
#pragma unroll
            for (int g = 0; g < 3; ++g) {
                float acc = 0.f;
#pragma unroll
                for (int j = 0; j < 8; ++j)
                    acc += (float)q8[h][j] * (float)k8[g][j];
                s[h][g] += acc;
            }
    }

    // wave butterfly reduce each of the 9 partial dots
#pragma unroll
    for (int h = 0; h < 3; ++h)
#pragma unroll
        for (int g = 0; g < 3; ++g) {
            float val = s[h][g];
#pragma unroll
            for (int off = 32; off > 0; off >>= 1)
                val += __shfl_xor(val, off, 64);
            s[h][g] = val;
        }

    // softmax over g (scale = 1/sqrt(1024) = 1/32)
    float w[3][3];
    const float scale = 0.03125f;
#pragma unroll
    for (int h = 0; h < 3; ++h) {
        float s0 = s[h][0] * scale, s1 = s[h][1] * scale, s2 = s[h][2] * scale;
        float mx = fmaxf(s0, fmaxf(s1, s2));
        float e0 = __expf(s0 - mx), e1 = __expf(s1 - mx), e2 = __expf(s2 - mx);
        float inv = 1.f / (e0 + e1 + e2);
        w[h][0] = e0 * inv; w[h][1] = e1 * inv; w[h][2] = e2 * inv;
    }

    // out[h,d] = sum_g w[h][g] * V[g,d]
#pragma unroll
    for (int it = 0; it < 2; ++it) {
        const int d0 = it * 512 + lane * 8;
        bf16x8 v8[3];
#pragma unroll
        for (int g = 0; g < 3; ++g)
            v8[g] = *reinterpret_cast<const bf16x8*>(vr + g * 1024 + d0);
#pragma unroll
        for (int h = 0; h < 3; ++h) {
            float o[8];
#pragma unroll
            for (int j = 0; j < 8; ++j)
                o[j] = w[h][0] * (float)v8[0][j] + w[h][1] * (float)v8[1][j] +
                       w[h][2] * (float)v8[2][j];
            float* op = out + b * DIM + h * 1024 + d0;
            float4 lo = {o[0], o[1], o[2], o[3]};
            float4 hi = {o[4], o[5], o[6], o[7]};
            *reinterpret_cast<float4*>(op) = lo;
            *reinterpret_cast<float4*>(op + 4) = hi;
        }
    }
}

// ---------------------------------------------------------------------------
extern "C" void kernel_launch(void* const* d_in, const int* in_sizes, int n_in,
                              void* d_out, int out_size, void* d_ws,
                              size_t ws_size, hipStream_t stream) {
    const float* x  = (const float*)d_in[0];
    const float* sa = (const float*)d_in[1];
    const float* Wq = (const float*)d_in[2];
    const float* bq = (const float*)d_in[3];
    const float* Wk = (const float*)d_in[4];
    const float* bk = (const float*)d_in[5];
    const float* Wv = (const float*)d_in[6];
    const float* bv = (const float*)d_in[7];
    float* out = (float*)d_out;

    const size_t B = BROWS, D = DIM;
    __bf16* ws  = (__bf16*)d_ws;
    __bf16* xb  = ws;              // B*D
    __bf16* sb  = xb + B * D;      // B*D
    __bf16* wqb = sb + B * D;      // D*D
    __bf16* wkb = wqb + D * D;
    __bf16* wvb = wkb + D * D;
    __bf16* qo  = wvb + D * D;     // B*D
    __bf16* ko  = qo + B * D;
    __bf16* vo  = ko + B * D;
    // total: 5*B*D + 3*D*D bf16 = ~534 MB

    const int nBD8 = (int)(B * D / 8);   // 6291456
    const int nDD8 = (int)(D * D / 8);   // 1179648

    cast_f32_bf16<<<nBD8 / 256, 256, 0, stream>>>(x, xb, nBD8);
    cast_f32_bf16<<<nBD8 / 256, 256, 0, stream>>>(sa, sb, nBD8);
    cast_f32_bf16<<<nDD8 / 256, 256, 0, stream>>>(Wq, wqb, nDD8);
    cast_f32_bf16<<<nDD8 / 256, 256, 0, stream>>>(Wk, wkb, nDD8);
    cast_f32_bf16<<<nDD8 / 256, 256, 0, stream>>>(Wv, wvb, nDD8);

    gemm_qkv<<<2304, 512, 0, stream>>>(xb, sb, wqb, wkb, wvb, bq, bk, bv,
                                       qo, ko, vo);

    attn_kernel<<<BROWS / 4, 256, 0, stream>>>(qo, ko, vo, out);
}